// Round 7
// baseline (108.867 us; speedup 1.0000x reference)
//
#include <hip/hip_runtime.h>
#include <hip/hip_bf16.h>
#include <math.h>

#define BS 8
#define NPTS 8192
#define NM 32
#define D 512
#define NT 256                // total masks
#define KC 16                 // K-split factor
#define KCHUNK (NPTS/KC)      // 512 points per block
#define TILES (KCHUNK/32)     // 16 k-tiles of 32
#define DC 8                  // D-chunks (64 dims per block, 16 per wave)
#define NWORDS (NPTS/32)      // 256 uints per mask row

#define LOG2E 1.44269504088896f
#define LN2   0.69314718055995f

typedef short short8 __attribute__((ext_vector_type(8)));
typedef float f32x4 __attribute__((ext_vector_type(4)));

// ws layout (floats):
static constexpr size_t OFF_SUMF = 0;                        // [NT][D] atomic acc (zeroed by kp)
static constexpr size_t OFF_CNTS = OFF_SUMF + (size_t)NT*D;  // [NT]
static constexpr size_t OFF_BITS = OFF_CNTS + NT;            // [NT][NWORDS] uints (256KB)
static constexpr size_t OFF_LOG  = OFF_BITS + (size_t)NT*NWORDS;
static constexpr size_t OFF_RLSE = OFF_LOG + (size_t)NT*NT;  // [NT]

__device__ __forceinline__ short bf16_rne(float f) {
  return __builtin_bit_cast(short, __float2bfloat16(f));
}

#define GLOAD_LDS16(g, l) __builtin_amdgcn_global_load_lds( \
    (const __attribute__((address_space(1))) void*)(g),     \
    (__attribute__((address_space(3))) void*)(l), 16, 0, 0)

// KP: bit-pack mask (8MB f32 -> 256KB bits), exact popcount counts, zero sumf.
__global__ __launch_bounds__(256) void kp_prep(const float* __restrict__ mpts,
                                               unsigned int* __restrict__ mbits,
                                               float* __restrict__ cnts,
                                               float* __restrict__ sumf) {
  const int n = blockIdx.x;
  const int t = threadIdx.x;
  const float4* mp = (const float4*)(mpts + ((size_t)n << 13) + t * 32);
  unsigned int u = 0;
  #pragma unroll
  for (int q = 0; q < 8; ++q) {
    const float4 v = mp[q];
    u |= (v.x != 0.f ? 1u : 0u) << (q * 4 + 0);
    u |= (v.y != 0.f ? 1u : 0u) << (q * 4 + 1);
    u |= (v.z != 0.f ? 1u : 0u) << (q * 4 + 2);
    u |= (v.w != 0.f ? 1u : 0u) << (q * 4 + 3);
  }
  mbits[n * NWORDS + t] = u;
  ((float2*)(sumf + ((size_t)n << 9)))[t] = make_float2(0.f, 0.f);
  int c = __popc(u);
  #pragma unroll
  for (int o = 32; o > 0; o >>= 1) c += __shfl_down(c, o, 64);
  __shared__ int red[4];
  if ((t & 63) == 0) red[t >> 6] = c;
  __syncthreads();
  if (t == 0) cnts[n] = (float)(red[0] + red[1] + red[2] + red[3]);
}

// K1: masked-sum einsum, bf16 MFMA. Wave-private LDS staging (no __syncthreads):
// each wave owns a 2x2KB ring; counted vmcnt(2) keeps next-tile loads in flight.
// B-frag read at phys row lhi*8+(j^par), par=lhi&1 -> 2-way banks (free);
// A bits use the same k-permutation (adjacent-bit swap when par=1).
// Grid: b(8) x kc(16) x dc(8) = 1024 blocks -> 4 blocks/CU, 16 waves/CU.
__global__ __launch_bounds__(256, 4) void k1_mfma(const float* __restrict__ net,
                                                  const unsigned int* __restrict__ mbits,
                                                  float* __restrict__ sumf) {
  __shared__ float wt[4][2][512];   // [wave][buf][32 rows x 16 d] = 16KB
  const int bx = blockIdx.x;
  const int dc = bx & 7;
  const int kc = (bx >> 3) & 15;
  const int b  = bx >> 7;
  const int w    = threadIdx.x >> 6;
  const int lane = threadIdx.x & 63;
  const int lhi = lane >> 4, llo = lane & 15;
  const int par = lhi & 1;
  const int k0 = kc * KCHUNK;
  const int d0w = dc * 64 + w * 16;

  // preload all mask words for this block's 512 points (16 uints per row)
  const unsigned int* r0p = mbits + (size_t)(b * NM + llo) * NWORDS + kc * TILES;
  const uint4 m00 = *(const uint4*)(r0p + 0);
  const uint4 m01 = *(const uint4*)(r0p + 4);
  const uint4 m02 = *(const uint4*)(r0p + 8);
  const uint4 m03 = *(const uint4*)(r0p + 12);
  const unsigned int* r1p = r0p + (size_t)16 * NWORDS;
  const uint4 m10 = *(const uint4*)(r1p + 0);
  const uint4 m11 = *(const uint4*)(r1p + 4);
  const uint4 m12 = *(const uint4*)(r1p + 8);
  const uint4 m13 = *(const uint4*)(r1p + 12);
  const unsigned int w0[16] = {m00.x,m00.y,m00.z,m00.w, m01.x,m01.y,m01.z,m01.w,
                               m02.x,m02.y,m02.z,m02.w, m03.x,m03.y,m03.z,m03.w};
  const unsigned int w1[16] = {m10.x,m10.y,m10.z,m10.w, m11.x,m11.y,m11.z,m11.w,
                               m12.x,m12.y,m12.z,m12.w, m13.x,m13.y,m13.z,m13.w};

  // staging sources: lane l -> row (l>>2) within segment, granule l&3 (16B)
  const float* s0 = net + ((size_t)(b * NPTS + k0 + (lane >> 2)) << 9)
                        + d0w + ((lane & 3) << 2);
  const float* s1 = s0 + ((size_t)16 << 9);

  f32x4 acc0 = {0.f, 0.f, 0.f, 0.f};
  f32x4 acc1 = {0.f, 0.f, 0.f, 0.f};

  // issue first tile's stage
  GLOAD_LDS16(s0, &wt[w][0][0]);
  GLOAD_LDS16(s1, &wt[w][0][256]);
  s0 += (size_t)32 << 9; s1 += (size_t)32 << 9;

  const int rb = lhi * 128 + (par << 4) + llo;   // phys read base (xor'd with j<<4)
  const float* wtw = &wt[w][0][0];

  #pragma unroll
  for (int t = 0; t < TILES; ++t) {
    const int cur = t & 1;
    if (t > 0) {   // drain this wave's prior ds_reads before overwriting their buffer
      asm volatile("s_waitcnt lgkmcnt(0)" ::: "memory");
    }
    if (t + 1 < TILES) {
      GLOAD_LDS16(s0, &wt[w][cur ^ 1][0]);
      GLOAD_LDS16(s1, &wt[w][cur ^ 1][256]);
      s0 += (size_t)32 << 9; s1 += (size_t)32 << 9;
      asm volatile("s_waitcnt vmcnt(2)" ::: "memory");   // tile t landed; t+1 in flight
    } else {
      asm volatile("s_waitcnt vmcnt(0)" ::: "memory");   // last tile
    }
    __builtin_amdgcn_sched_barrier(0);

    // B frag: phys row lhi*8 + (j^par), col llo  (2-way banks = free)
    float bp[8];
    #pragma unroll
    for (int j = 0; j < 8; ++j) bp[j] = wtw[(size_t)cur * 512 + (rb ^ (j << 4))];

    short8 bf, a0f, a1f;
    #pragma unroll
    for (int j = 0; j < 8; ++j) bf[j] = bf16_rne(bp[j]);

    // A bits with matching k-permutation: bit_j = us >> (j^par)
    unsigned int us0 = (w0[t] >> (lhi * 8)) & 0xffu;
    unsigned int us1 = (w1[t] >> (lhi * 8)) & 0xffu;
    const unsigned int sw0 = ((us0 & 0x55u) << 1) | ((us0 >> 1) & 0x55u);
    const unsigned int sw1 = ((us1 & 0x55u) << 1) | ((us1 >> 1) & 0x55u);
    us0 = par ? sw0 : us0;
    us1 = par ? sw1 : us1;
    #pragma unroll
    for (int j = 0; j < 8; ++j) {
      a0f[j] = (short)(-(int)((us0 >> j) & 1u) & 0x3F80);
      a1f[j] = (short)(-(int)((us1 >> j) & 1u) & 0x3F80);
    }

    acc0 = __builtin_amdgcn_mfma_f32_16x16x32_bf16(a0f, bf, acc0, 0, 0, 0);
    acc1 = __builtin_amdgcn_mfma_f32_16x16x32_bf16(a1f, bf, acc1, 0, 0, 0);
  }

  // C/D: col = llo (d), row = lhi*4 + j (m); atomic accumulate into sumf
  float* sp = sumf + (((size_t)(b * NM)) << 9) + d0w + llo;
  #pragma unroll
  for (int j = 0; j < 4; ++j) {
    atomicAdd(sp + ((size_t)(lhi * 4 + j) << 9),      acc0[j]);
    atomicAdd(sp + ((size_t)(16 + lhi * 4 + j) << 9), acc1[j]);
  }
}

// K2: logits row-panel (16 rows x 256 cols) via bf16 MFMA + fused row-LSE.
// Grid: 16 blocks x 4 waves (wave w owns cols w*64..w*64+63).
__global__ __launch_bounds__(256) void k2_logits(const float* __restrict__ embs,
                                                 const float* __restrict__ sumf,
                                                 const float* __restrict__ cnts,
                                                 const float* __restrict__ lsc,
                                                 float* __restrict__ logits,
                                                 float* __restrict__ rowlse) {
  const int i0 = blockIdx.x * 16;
  const int w = threadIdx.x >> 6, lane = threadIdx.x & 63;
  const int lhi = lane >> 4, llo = lane & 15;

  const float* ea = embs + ((size_t)(i0 + llo) << 9) + lhi * 8;
  const float* sv = sumf + ((size_t)(w * 64 + llo) << 9) + lhi * 8;
  f32x4 acc[4] = {{0.f,0.f,0.f,0.f},{0.f,0.f,0.f,0.f},{0.f,0.f,0.f,0.f},{0.f,0.f,0.f,0.f}};
  #pragma unroll 4
  for (int kk = 0; kk < 16; ++kk) {
    const float4 e0 = *(const float4*)(ea);
    const float4 e1 = *(const float4*)(ea + 4);
    const float ev[8] = {e0.x,e0.y,e0.z,e0.w,e1.x,e1.y,e1.z,e1.w};
    short8 af;
    #pragma unroll
    for (int j = 0; j < 8; ++j) af[j] = bf16_rne(ev[j]);
    #pragma unroll
    for (int tj = 0; tj < 4; ++tj) {
      const float* p = sv + ((size_t)tj << 13);   // +tj*16 rows
      const float4 v0 = *(const float4*)(p);
      const float4 v1 = *(const float4*)(p + 4);
      const float vv[8] = {v0.x,v0.y,v0.z,v0.w,v1.x,v1.y,v1.z,v1.w};
      short8 vf;
      #pragma unroll
      for (int j = 0; j < 8; ++j) vf[j] = bf16_rne(vv[j]);
      acc[tj] = __builtin_amdgcn_mfma_f32_16x16x32_bf16(af, vf, acc[tj], 0, 0, 0);
    }
    ea += 32; sv += 32;
  }

  const float scale = expf(lsc[0]);
  float lg[4][4];
  #pragma unroll
  for (int tj = 0; tj < 4; ++tj) {
    const int c = w * 64 + tj * 16 + llo;
    const float ic = scale / (cnts[c] + 1e-12f);
    #pragma unroll
    for (int r = 0; r < 4; ++r) lg[tj][r] = acc[tj][r] * ic;
  }
  float* lp = logits + (size_t)i0 * NT;
  #pragma unroll
  for (int tj = 0; tj < 4; ++tj)
    #pragma unroll
    for (int r = 0; r < 4; ++r)
      lp[(size_t)(lhi * 4 + r) * NT + w * 64 + tj * 16 + llo] = lg[tj][r];

  // fused row-LSE
  __shared__ float sred[2][4][16];
  __shared__ float gmax[16];
  float pm[4];
  #pragma unroll
  for (int r = 0; r < 4; ++r) {
    pm[r] = fmaxf(fmaxf(lg[0][r], lg[1][r]), fmaxf(lg[2][r], lg[3][r]));
    #pragma unroll
    for (int o = 1; o < 16; o <<= 1) pm[r] = fmaxf(pm[r], __shfl_xor(pm[r], o, 64));
  }
  if (llo == 0) {
    #pragma unroll
    for (int r = 0; r < 4; ++r) sred[0][w][lhi * 4 + r] = pm[r];
  }
  __syncthreads();
  if (threadIdx.x < 16)
    gmax[threadIdx.x] = fmaxf(fmaxf(sred[0][0][threadIdx.x], sred[0][1][threadIdx.x]),
                              fmaxf(sred[0][2][threadIdx.x], sred[0][3][threadIdx.x]));
  __syncthreads();
  float ps[4];
  #pragma unroll
  for (int r = 0; r < 4; ++r) {
    const float m2 = gmax[lhi * 4 + r] * LOG2E;
    ps[r] = exp2f(lg[0][r] * LOG2E - m2) + exp2f(lg[1][r] * LOG2E - m2)
          + exp2f(lg[2][r] * LOG2E - m2) + exp2f(lg[3][r] * LOG2E - m2);
    #pragma unroll
    for (int o = 1; o < 16; o <<= 1) ps[r] += __shfl_xor(ps[r], o, 64);
  }
  if (llo == 0) {
    #pragma unroll
    for (int r = 0; r < 4; ++r) sred[1][w][lhi * 4 + r] = ps[r];
  }
  __syncthreads();
  if (threadIdx.x < 16) {
    const float s = sred[1][0][threadIdx.x] + sred[1][1][threadIdx.x]
                  + sred[1][2][threadIdx.x] + sred[1][3][threadIdx.x];
    rowlse[i0 + threadIdx.x] = (gmax[threadIdx.x] * LOG2E + log2f(s)) * LN2;
  }
}

// K3: coalesced col-LSE + diag + final nonzero-avg -> scalar. One block.
__global__ __launch_bounds__(256) void k3_loss(const float* __restrict__ logits,
                                               const float* __restrict__ rowlse,
                                               const float* __restrict__ cnts,
                                               float* __restrict__ out) {
  const int i = threadIdx.x;
  float mc = -1e30f;
  #pragma unroll 8
  for (int k = 0; k < NT; ++k) mc = fmaxf(mc, logits[(size_t)k * NT + i]);
  const float m2 = mc * LOG2E;
  float sc = 0.f;
  #pragma unroll 8
  for (int k = 0; k < NT; ++k) sc += exp2f(logits[(size_t)k * NT + i] * LOG2E - m2);
  const float collse = (m2 + log2f(sc)) * LN2;

  const float diag = logits[(size_t)i * NT + i];
  const bool valid = cnts[i] > 0.f;
  const float tl = valid ? (rowlse[i] - diag) : 0.f;
  const float pl = valid ? (collse - diag) : 0.f;

  __shared__ float red[4][256];
  red[0][i] = tl;
  red[1][i] = (tl > 0.f) ? 1.f : 0.f;
  red[2][i] = pl;
  red[3][i] = (pl > 0.f) ? 1.f : 0.f;
  __syncthreads();
  for (int st = 128; st > 0; st >>= 1) {
    if (i < st) {
      red[0][i] += red[0][i + st];
      red[1][i] += red[1][i + st];
      red[2][i] += red[2][i + st];
      red[3][i] += red[3][i + st];
    }
    __syncthreads();
  }
  if (i == 0) {
    const float a1 = (red[1][0] > 0.f) ? red[0][0] / fmaxf(red[1][0], 1.f) : 0.f;
    const float a2 = (red[3][0] > 0.f) ? red[2][0] / fmaxf(red[3][0], 1.f) : 0.f;
    out[0] = 0.5f * (a1 + a2);
  }
}

extern "C" void kernel_launch(void* const* d_in, const int* in_sizes, int n_in,
                              void* d_out, int out_size, void* d_ws, size_t ws_size,
                              hipStream_t stream) {
  const float* net  = (const float*)d_in[0];
  const float* embs = (const float*)d_in[1];
  const float* mpts = (const float*)d_in[2];
  const float* lsc  = (const float*)d_in[3];

  float* ws     = (float*)d_ws;
  float* sumf   = ws + OFF_SUMF;
  float* cnts   = ws + OFF_CNTS;
  unsigned int* mbits = (unsigned int*)(ws + OFF_BITS);
  float* logits = ws + OFF_LOG;
  float* rowlse = ws + OFF_RLSE;
  float* outp   = (float*)d_out;

  kp_prep<<<dim3(NT), dim3(256), 0, stream>>>(mpts, mbits, cnts, sumf);
  k1_mfma<<<dim3(BS * KC * DC), dim3(256), 0, stream>>>(net, mbits, sumf);
  k2_logits<<<dim3(16), dim3(256), 0, stream>>>(embs, sumf, cnts, lsc, logits, rowlse);
  k3_loss<<<dim3(1), dim3(256), 0, stream>>>(logits, rowlse, cnts, outp);
}